// Round 7
// baseline (553.024 us; speedup 1.0000x reference)
//
#include <hip/hip_runtime.h>
#include <hip/hip_bf16.h>

#define ENC_DIM 2048
#define DEC_DIM 512
#define ATT_DIM 512
#define BATCH   128
#define NPIX    196
#define NROWS   (BATCH * NPIX)   // 25088

typedef short bf16x8 __attribute__((ext_vector_type(8)));
typedef float f32x4  __attribute__((ext_vector_type(4)));
typedef unsigned short u16x8 __attribute__((ext_vector_type(8)));

__device__ __forceinline__ unsigned short f2bf(float f) {
    union { float f; unsigned u; } v; v.f = f;
    unsigned r = v.u + 0x7fffu + ((v.u >> 16) & 1u);   // RNE
    return (unsigned short)(r >> 16);
}

__device__ __forceinline__ short bfc(float f) {
    union { __hip_bfloat16 h; short s; } v;
    v.h = __float2bfloat16(f);                          // RNE, = f2bf
    return v.s;
}

// async global->LDS, 16 B per lane; dst is wave-uniform base + lane*16
__device__ __forceinline__ void gload16(const void* g, void* l) {
    __builtin_amdgcn_global_load_lds(
        (const __attribute__((address_space(1))) unsigned int*)g,
        (__attribute__((address_space(3))) unsigned int*)l, 16, 0, 0);
}

// ---------------------------------------------------------------- prep:
// 512 blocks x 256 thr, split grid (both halves depend only on inputs):
//   blocks   0..255 : Wt[a][e] = bf16(W_enc[e][a])  (LDS-tiled transpose)
//   blocks 256..511 : att2'[b][c] = dh[b]@W_dec[:,c] + b_dec[c] + b_enc[c]
//   blocks   0..97  : score[gid] = b_full   (98*256 = 25088 exactly)
//   block 0         : cnt[0..127] = 0       (per-batch completion counters)
__global__ void prep(const float* __restrict__ W_enc, const float* __restrict__ dh,
                     const float* __restrict__ W_dec, const float* __restrict__ b_dec,
                     const float* __restrict__ b_enc, const float* __restrict__ b_full,
                     unsigned short* __restrict__ Wt, float* __restrict__ att2,
                     float* __restrict__ score, int* __restrict__ cnt) {
    __shared__ float ts[64][65];
    const int bid = blockIdx.x, t = threadIdx.x;

    if (bid < 98) {
        const int gid = bid * 256 + t;
        score[gid] = b_full[0];
    }
    if (bid == 0 && t < BATCH) cnt[t] = 0;

    if (bid < 256) {
        // ---- transpose tile
        const int a0 = (bid & 7) * 64;
        const int e0 = (bid >> 3) * 64;
        const int tx = t & 15;
        const int ty = t >> 4;
        #pragma unroll
        for (int p = 0; p < 4; ++p) {
            const int e = ty + p * 16;
            const float4 v = *(const float4*)&W_enc[(size_t)(e0 + e) * ATT_DIM + a0 + tx * 4];
            ts[e][tx * 4 + 0] = v.x; ts[e][tx * 4 + 1] = v.y;
            ts[e][tx * 4 + 2] = v.z; ts[e][tx * 4 + 3] = v.w;
        }
        __syncthreads();
        #pragma unroll
        for (int p = 0; p < 4; ++p) {
            const int a = ty + p * 16;
            ushort4 u;
            u.x = f2bf(ts[tx * 4 + 0][a]);
            u.y = f2bf(ts[tx * 4 + 1][a]);
            u.z = f2bf(ts[tx * 4 + 2][a]);
            u.w = f2bf(ts[tx * 4 + 3][a]);
            *(ushort4*)&Wt[(size_t)(a0 + a) * ENC_DIM + e0 + tx * 4] = u;
        }
    } else {
        // ---- att2 (k1 body, verified): kb in [0,256)
        float* dhs = &ts[0][0];                  // 512-float scratch
        const int kb = bid - 256;
        const int b  = kb >> 1;
        const int c  = (kb & 1) * 256 + t;
        dhs[t]       = dh[b * DEC_DIM + t];
        dhs[t + 256] = dh[b * DEC_DIM + t + 256];
        __syncthreads();
        float acc0 = 0.f, acc1 = 0.f;
        #pragma unroll 8
        for (int d = 0; d < 256; ++d) {
            acc0 += dhs[d]       * W_dec[d * ATT_DIM + c];
            acc1 += dhs[d + 256] * W_dec[(d + 256) * ATT_DIM + c];
        }
        att2[b * ATT_DIM + c] = acc0 + acc1 + b_dec[c] + b_enc[c];
    }
}

// ---------------------------------------------------------------- k2g:
// R3-verbatim GEMM core (136 us verified) + tail-finisher.
// GEMM: BM=128, BN=128, BK=64, 4 waves, acc[4][4], XCD-chunked swizzle;
//   A via global_load_lds fp32 (swizzled source, cvt on read), B via
//   global_load_lds bf16 (swizzled source), both-sides XOR involution.
// Finisher: after score atomics, threadfence + per-batch counter; the block
//   completing a batch (target = 4 x tiles-overlapping-batch) computes that
//   batch's softmax + awe in-block (scores via agent-scope atomic loads,
//   enc L3-warm). Removes the k4 launch entirely.
__launch_bounds__(256, 3)
__global__ void k2g(const float* __restrict__ enc, const unsigned short* __restrict__ Wt,
                    const float* __restrict__ att2, const float* __restrict__ W_full,
                    float* __restrict__ score, int* __restrict__ cnt,
                    float* __restrict__ alpha, float* __restrict__ awe) {
    __shared__ __align__(16) float          Asf[128 * 64];   // 32768 B, linear+swz
    __shared__ __align__(16) unsigned short Bs [128 * 64];   // 16384 B, linear+swz
    __shared__ float att2s[2][128];
    __shared__ float wfs[128];
    __shared__ int   finb[2];

    const int t = threadIdx.x;
    const int tile = (blockIdx.x & 7) * 98 + (blockIdx.x >> 3);   // bijective on [0,784)
    const int n0   = (tile & 3) * 128;
    const int row0 = (tile >> 2) * 128;
    const int b0   = row0 / NPIX;
    const int rows_left = (b0 + 1) * NPIX - row0;

    if (t < 128) {
        att2s[0][t] = att2[b0 * ATT_DIM + n0 + t];
        att2s[1][t] = (b0 + 1 < BATCH) ? att2[(b0 + 1) * ATT_DIM + n0 + t] : 0.f;
        wfs[t]      = W_full[n0 + t];
    }

    const int w    = t >> 6;         // wave 0..3
    const int lane = t & 63;
    const int q    = lane >> 4;      // 0..3
    const int cl   = lane & 15;
    const int wm   = (w >> 1) * 64;  // wave's row offset (0/64)
    const int wn   = (w & 1) * 64;   // wave's col offset (0/64)

    f32x4 acc[4][4] = {};

    // A staging sources (global_load_lds, fp32, swizzled source)
    const int r4 = lane >> 4;        // 0..3
    const int sl = lane & 15;
    const float* aS0 = enc + (size_t)(row0 + w * 32 + r4)     * ENC_DIM + ((sl ^ r4)       << 2);
    const float* aS1 = enc + (size_t)(row0 + w * 32 + 4 + r4) * ENC_DIM + ((sl ^ (4 + r4)) << 2);

    // B staging source (bf16, swizzled source)
    const int br = lane >> 3;                       // 0..7
    const int bc = ((lane & 7) ^ br) * 8;           // swizzled col (shorts)
    const unsigned short* WtB = Wt + (size_t)(n0 + w * 32 + br) * ENC_DIM + bc;

    // Hoisted A-fragment byte addresses (R3 derivation)
    unsigned ab[4], ab2[4];
    #pragma unroll
    for (int mi = 0; mi < 4; ++mi) {
        unsigned base = ((unsigned)(wm + mi * 16 + cl) << 8) + ((unsigned)(cl & 7) << 4);
        base ^= (unsigned)(q << 5);
        ab[mi]  = base;
        ab2[mi] = base ^ 16u;
    }
    const char* Ab = (const char*)Asf;

    for (int kk = 0; kk < ENC_DIM; kk += 64) {
        __syncthreads();   // previous iteration's frag reads complete
        #pragma unroll
        for (int i = 0; i < 4; ++i)
            gload16(WtB + (size_t)i * 8 * ENC_DIM + kk, &Bs[(w * 32 + i * 8) * 64]);
        #pragma unroll
        for (int i = 0; i < 4; ++i) {
            gload16(aS0 + (size_t)i * 8 * ENC_DIM + kk, &Asf[(w * 32 + i * 8)     * 64]);
            gload16(aS1 + (size_t)i * 8 * ENC_DIM + kk, &Asf[(w * 32 + i * 8 + 4) * 64]);
        }
        __syncthreads();   // tile visible (barrier drains vmcnt)

        #pragma unroll
        for (int h = 0; h < 2; ++h) {   // two 32-wide K halves
            bf16x8 af[4], bfr[4];
            #pragma unroll
            for (int mi = 0; mi < 4; ++mi) {
                const f32x4 fa = *(const f32x4*)(Ab + ab[mi]  + h * 128);
                const f32x4 fb = *(const f32x4*)(Ab + ab2[mi] + h * 128);
                bf16x8 u;
                u[0] = bfc(fa[0]); u[1] = bfc(fa[1]); u[2] = bfc(fa[2]); u[3] = bfc(fa[3]);
                u[4] = bfc(fb[0]); u[5] = bfc(fb[1]); u[6] = bfc(fb[2]); u[7] = bfc(fb[3]);
                af[mi] = u;
            }
            #pragma unroll
            for (int i = 0; i < 4; ++i)
                bfr[i] = *(const bf16x8*)&Bs[(wn + i * 16 + cl) * 64
                                             + (((h * 4 + q) ^ (cl & 7)) * 8)];
            #pragma unroll
            for (int mi = 0; mi < 4; ++mi)
                #pragma unroll
                for (int ni = 0; ni < 4; ++ni)
                    acc[mi][ni] = __builtin_amdgcn_mfma_f32_16x16x32_bf16(
                        af[mi], bfr[ni], acc[mi][ni], 0, 0, 0);
        }
    }

    // ---- epilogue: relu(att1 + att2') * W_full, reduce, atomic scores
    #pragma unroll
    for (int mi = 0; mi < 4; ++mi) {
        float rs[4];
        #pragma unroll
        for (int i = 0; i < 4; ++i) {
            const int lr  = wm + mi * 16 + q * 4 + i;         // local row
            const int sel = (lr >= rows_left) ? 1 : 0;
            float sum = 0.f;
            #pragma unroll
            for (int ni = 0; ni < 4; ++ni) {
                const int j = wn + ni * 16 + cl;              // local col 0..127
                float v = acc[mi][ni][i] + att2s[sel][j];
                v = fmaxf(v, 0.f);
                sum += v * wfs[j];
            }
            rs[i] = sum;
        }
        #pragma unroll
        for (int o = 1; o < 16; o <<= 1) {
            #pragma unroll
            for (int i = 0; i < 4; ++i) rs[i] += __shfl_xor(rs[i], o);
        }
        if (cl == 0) {
            #pragma unroll
            for (int i = 0; i < 4; ++i) {
                const int r = row0 + wm + mi * 16 + q * 4 + i;
                atomicAdd(&score[r], rs[i]);
            }
        }
    }

    // ---- completion protocol: release our atomics, then count.
    __threadfence();          // every thread: orders its own score atomics
    __syncthreads();          // all block atomics + fences done
    if (t == 0) {
        finb[0] = -1; finb[1] = -1;
        {   // batch b0: target = 4 * (#128-row tiles overlapping batch b0)
            const int first = (b0 * NPIX) >> 7, last = (b0 * NPIX + NPIX - 1) >> 7;
            if (atomicAdd(&cnt[b0], 1) + 1 == 4 * (last - first + 1)) finb[0] = b0;
        }
        if (rows_left < 128) {   // also touches b0+1 (< BATCH by construction)
            const int b1 = b0 + 1;
            const int first = (b1 * NPIX) >> 7, last = (b1 * NPIX + NPIX - 1) >> 7;
            if (atomicAdd(&cnt[b1], 1) + 1 == 4 * (last - first + 1)) finb[1] = b1;
        }
    }
    __syncthreads();

    // ---- finisher: softmax + awe for any batch this block completed.
    #pragma unroll
    for (int j = 0; j < 2; ++j) {
        const int fb = finb[j];
        if (fb < 0) continue;
        float* sA  = (float*)Bs;        // 196 floats (Bs free after barrier)
        float* red = &att2s[0][0];      // 4 floats  (att2s free after barrier)
        const int wv = t >> 6;
        const float x = (t < NPIX)
            ? __hip_atomic_load(&score[fb * NPIX + t], __ATOMIC_RELAXED,
                                __HIP_MEMORY_SCOPE_AGENT)
            : -INFINITY;
        float m = x;
        #pragma unroll
        for (int o = 32; o >= 1; o >>= 1) m = fmaxf(m, __shfl_xor(m, o));
        if (lane == 0) red[wv] = m;
        __syncthreads();
        m = fmaxf(fmaxf(red[0], red[1]), fmaxf(red[2], red[3]));
        const float e = (t < NPIX) ? __expf(x - m) : 0.f;
        float s = e;
        #pragma unroll
        for (int o = 32; o >= 1; o >>= 1) s += __shfl_xor(s, o);
        __syncthreads();
        if (lane == 0) red[wv] = s;
        __syncthreads();
        s = red[0] + red[1] + red[2] + red[3];
        const float a = e / s;
        if (t < NPIX) {
            sA[t] = a;
            alpha[fb * NPIX + t] = a;
        }
        __syncthreads();
        // awe: thread t owns cols [t*8, t*8+8)
        const int c0 = t * 8;
        const float* base = enc + (size_t)fb * NPIX * ENC_DIM;
        f32x4 s0a = {}, s0b = {}, s1a = {}, s1b = {};
        #pragma unroll 4
        for (int p = 0; p < NPIX; p += 2) {      // 196 even
            const float w0 = sA[p], w1 = sA[p + 1];
            s0a += w0 * *(const f32x4*)(base + (size_t)p       * ENC_DIM + c0);
            s1a += w0 * *(const f32x4*)(base + (size_t)p       * ENC_DIM + c0 + 4);
            s0b += w1 * *(const f32x4*)(base + (size_t)(p + 1) * ENC_DIM + c0);
            s1b += w1 * *(const f32x4*)(base + (size_t)(p + 1) * ENC_DIM + c0 + 4);
        }
        *(f32x4*)&awe[(size_t)fb * ENC_DIM + c0]     = s0a + s0b;
        *(f32x4*)&awe[(size_t)fb * ENC_DIM + c0 + 4] = s1a + s1b;
        __syncthreads();   // scratch reuse safety for j=1
    }
}

// ----------------------------------------------------------------
extern "C" void kernel_launch(void* const* d_in, const int* in_sizes, int n_in,
                              void* d_out, int out_size, void* d_ws, size_t ws_size,
                              hipStream_t stream) {
    const float* enc    = (const float*)d_in[0];   // [128,196,2048]
    const float* dh     = (const float*)d_in[1];   // [128,512]
    const float* W_enc  = (const float*)d_in[2];   // [2048,512]
    const float* b_enc  = (const float*)d_in[3];   // [512]
    const float* W_dec  = (const float*)d_in[4];   // [512,512]
    const float* b_dec  = (const float*)d_in[5];   // [512]
    const float* W_full = (const float*)d_in[6];   // [512]
    const float* b_full = (const float*)d_in[7];   // scalar

    float* awe   = (float*)d_out;                  // [128,2048]
    float* alpha = awe + BATCH * ENC_DIM;          // [128,196] final output

    // workspace: Wt bf16 (2 MB) + att2 (256 KB) + score (100 KB) + cnt (512 B)
    unsigned short* Wt    = (unsigned short*)d_ws;
    float*          att2  = (float*)((char*)d_ws + (size_t)ATT_DIM * ENC_DIM * 2);
    float*          score = att2 + (size_t)BATCH * ATT_DIM;
    int*            cnt   = (int*)(score + NROWS);

    prep<<<512, 256, 0, stream>>>(W_enc, dh, W_dec, b_dec, b_enc, b_full,
                                  Wt, att2, score, cnt);
    k2g <<<784, 256, 0, stream>>>(enc, Wt, att2, W_full, score, cnt, alpha, awe);
}

// Round 8
// 391.224 us; speedup vs baseline: 1.4136x; 1.4136x over previous
//
#include <hip/hip_runtime.h>
#include <hip/hip_bf16.h>

#define ENC_DIM 2048
#define DEC_DIM 512
#define ATT_DIM 512
#define BATCH   128
#define NPIX    196
#define NROWS   (BATCH * NPIX)   // 25088

typedef short bf16x8 __attribute__((ext_vector_type(8)));
typedef float f32x4  __attribute__((ext_vector_type(4)));
typedef unsigned short u16x8 __attribute__((ext_vector_type(8)));

__device__ __forceinline__ unsigned short f2bf(float f) {
    union { float f; unsigned u; } v; v.f = f;
    unsigned r = v.u + 0x7fffu + ((v.u >> 16) & 1u);   // RNE
    return (unsigned short)(r >> 16);
}

__device__ __forceinline__ short bfc(float f) {
    union { __hip_bfloat16 h; short s; } v;
    v.h = __float2bfloat16(f);                          // RNE, = f2bf
    return v.s;
}

// async global->LDS, 16 B per lane; dst is wave-uniform base + lane*16
__device__ __forceinline__ void gload16(const void* g, void* l) {
    __builtin_amdgcn_global_load_lds(
        (const __attribute__((address_space(1))) unsigned int*)g,
        (__attribute__((address_space(3))) unsigned int*)l, 16, 0, 0);
}

// ---------------------------------------------------------------- prep:
// 512 blocks x 256 thr, split grid (verified R7; both halves input-only):
//   blocks   0..255 : Wt[a][e] = bf16(W_enc[e][a])  (LDS-tiled transpose)
//   blocks 256..511 : att2'[b][c] = dh[b]@W_dec[:,c] + b_dec[c] + b_enc[c]
//   blocks   0..97  : score[gid] = b_full   (98*256 = 25088 exactly)
__global__ void prep(const float* __restrict__ W_enc, const float* __restrict__ dh,
                     const float* __restrict__ W_dec, const float* __restrict__ b_dec,
                     const float* __restrict__ b_enc, const float* __restrict__ b_full,
                     unsigned short* __restrict__ Wt, float* __restrict__ att2,
                     float* __restrict__ score) {
    __shared__ float ts[64][65];
    const int bid = blockIdx.x, t = threadIdx.x;

    if (bid < 98) score[bid * 256 + t] = b_full[0];

    if (bid < 256) {
        // ---- transpose tile (verified k0 body)
        const int a0 = (bid & 7) * 64;
        const int e0 = (bid >> 3) * 64;
        const int tx = t & 15;
        const int ty = t >> 4;
        #pragma unroll
        for (int p = 0; p < 4; ++p) {
            const int e = ty + p * 16;
            const float4 v = *(const float4*)&W_enc[(size_t)(e0 + e) * ATT_DIM + a0 + tx * 4];
            ts[e][tx * 4 + 0] = v.x; ts[e][tx * 4 + 1] = v.y;
            ts[e][tx * 4 + 2] = v.z; ts[e][tx * 4 + 3] = v.w;
        }
        __syncthreads();
        #pragma unroll
        for (int p = 0; p < 4; ++p) {
            const int a = ty + p * 16;
            ushort4 u;
            u.x = f2bf(ts[tx * 4 + 0][a]);
            u.y = f2bf(ts[tx * 4 + 1][a]);
            u.z = f2bf(ts[tx * 4 + 2][a]);
            u.w = f2bf(ts[tx * 4 + 3][a]);
            *(ushort4*)&Wt[(size_t)(a0 + a) * ENC_DIM + e0 + tx * 4] = u;
        }
    } else {
        // ---- att2 (verified k1 body): kb in [0,256)
        float* dhs = &ts[0][0];                  // 512-float scratch
        const int kb = bid - 256;
        const int b  = kb >> 1;
        const int c  = (kb & 1) * 256 + t;
        dhs[t]       = dh[b * DEC_DIM + t];
        dhs[t + 256] = dh[b * DEC_DIM + t + 256];
        __syncthreads();
        float acc0 = 0.f, acc1 = 0.f;
        #pragma unroll 8
        for (int d = 0; d < 256; ++d) {
            acc0 += dhs[d]       * W_dec[d * ATT_DIM + c];
            acc1 += dhs[d + 256] * W_dec[(d + 256) * ATT_DIM + c];
        }
        att2[b * ATT_DIM + c] = acc0 + acc1 + b_dec[c] + b_enc[c];
    }
}

// ---------------------------------------------------------------- k2:
// R3-VERBATIM (136 us measured): fused bf16 MFMA GEMM + relu + W_full
// reduction -> atomic partial scores.  BM=128, BN=128, BK=64, 4 waves,
// acc[4][4], XCD-chunked grid swizzle.  A staged via global_load_lds as
// fp32 (swizzled source, linear LDS dest, cvt on read side); B via
// global_load_lds bf16 (swizzled source); both-sides XOR involution.
__launch_bounds__(256, 3)
__global__ void k2_gemm(const float* __restrict__ enc, const unsigned short* __restrict__ Wt,
                        const float* __restrict__ att2, const float* __restrict__ W_full,
                        float* __restrict__ score) {
    __shared__ __align__(16) float          Asf[128 * 64];   // 32768 B, linear+swz
    __shared__ __align__(16) unsigned short Bs [128 * 64];   // 16384 B, linear+swz
    __shared__ float att2s[2][128];
    __shared__ float wfs[128];

    const int t = threadIdx.x;
    const int tile = (blockIdx.x & 7) * 98 + (blockIdx.x >> 3);   // bijective on [0,784)
    const int n0   = (tile & 3) * 128;
    const int row0 = (tile >> 2) * 128;
    const int b0   = row0 / NPIX;
    const int rows_left = (b0 + 1) * NPIX - row0;

    if (t < 128) {
        att2s[0][t] = att2[b0 * ATT_DIM + n0 + t];
        att2s[1][t] = (b0 + 1 < BATCH) ? att2[(b0 + 1) * ATT_DIM + n0 + t] : 0.f;
        wfs[t]      = W_full[n0 + t];
    }

    const int w    = t >> 6;         // wave 0..3
    const int lane = t & 63;
    const int q    = lane >> 4;      // 0..3
    const int cl   = lane & 15;
    const int wm   = (w >> 1) * 64;  // wave's row offset (0/64)
    const int wn   = (w & 1) * 64;   // wave's col offset (0/64)

    f32x4 acc[4][4] = {};

    // A staging sources (global_load_lds, fp32, swizzled source)
    const int r4 = lane >> 4;        // 0..3
    const int sl = lane & 15;
    const float* aS0 = enc + (size_t)(row0 + w * 32 + r4)     * ENC_DIM + ((sl ^ r4)       << 2);
    const float* aS1 = enc + (size_t)(row0 + w * 32 + 4 + r4) * ENC_DIM + ((sl ^ (4 + r4)) << 2);

    // B staging source (bf16, swizzled source)
    const int br = lane >> 3;                       // 0..7
    const int bc = ((lane & 7) ^ br) * 8;           // swizzled col (shorts)
    const unsigned short* WtB = Wt + (size_t)(n0 + w * 32 + br) * ENC_DIM + bc;

    // Hoisted A-fragment byte addresses (R3 derivation)
    unsigned ab[4], ab2[4];
    #pragma unroll
    for (int mi = 0; mi < 4; ++mi) {
        unsigned base = ((unsigned)(wm + mi * 16 + cl) << 8) + ((unsigned)(cl & 7) << 4);
        base ^= (unsigned)(q << 5);
        ab[mi]  = base;
        ab2[mi] = base ^ 16u;
    }
    const char* Ab = (const char*)Asf;

    for (int kk = 0; kk < ENC_DIM; kk += 64) {
        __syncthreads();   // previous iteration's frag reads complete
        // B: 4 x global_load_lds (8 rows each)
        #pragma unroll
        for (int i = 0; i < 4; ++i)
            gload16(WtB + (size_t)i * 8 * ENC_DIM + kk, &Bs[(w * 32 + i * 8) * 64]);
        // A: 8 x global_load_lds (4 rows each, fp32)
        #pragma unroll
        for (int i = 0; i < 4; ++i) {
            gload16(aS0 + (size_t)i * 8 * ENC_DIM + kk, &Asf[(w * 32 + i * 8)     * 64]);
            gload16(aS1 + (size_t)i * 8 * ENC_DIM + kk, &Asf[(w * 32 + i * 8 + 4) * 64]);
        }
        __syncthreads();   // tile visible (barrier drains vmcnt)

        #pragma unroll
        for (int h = 0; h < 2; ++h) {   // two 32-wide K halves
            bf16x8 af[4], bfr[4];
            #pragma unroll
            for (int mi = 0; mi < 4; ++mi) {
                const f32x4 fa = *(const f32x4*)(Ab + ab[mi]  + h * 128);
                const f32x4 fb = *(const f32x4*)(Ab + ab2[mi] + h * 128);
                bf16x8 u;
                u[0] = bfc(fa[0]); u[1] = bfc(fa[1]); u[2] = bfc(fa[2]); u[3] = bfc(fa[3]);
                u[4] = bfc(fb[0]); u[5] = bfc(fb[1]); u[6] = bfc(fb[2]); u[7] = bfc(fb[3]);
                af[mi] = u;
            }
            #pragma unroll
            for (int i = 0; i < 4; ++i)
                bfr[i] = *(const bf16x8*)&Bs[(wn + i * 16 + cl) * 64
                                             + (((h * 4 + q) ^ (cl & 7)) * 8)];
            #pragma unroll
            for (int mi = 0; mi < 4; ++mi)
                #pragma unroll
                for (int ni = 0; ni < 4; ++ni)
                    acc[mi][ni] = __builtin_amdgcn_mfma_f32_16x16x32_bf16(
                        af[mi], bfr[ni], acc[mi][ni], 0, 0, 0);
        }
    }

    // Epilogue: relu(att1 + att2') * W_full, reduce over this block's 128 cols.
    #pragma unroll
    for (int mi = 0; mi < 4; ++mi) {
        float rs[4];
        #pragma unroll
        for (int i = 0; i < 4; ++i) {
            const int lr  = wm + mi * 16 + q * 4 + i;         // local row
            const int sel = (lr >= rows_left) ? 1 : 0;
            float sum = 0.f;
            #pragma unroll
            for (int ni = 0; ni < 4; ++ni) {
                const int j = wn + ni * 16 + cl;              // local col 0..127
                float v = acc[mi][ni][i] + att2s[sel][j];
                v = fmaxf(v, 0.f);
                sum += v * wfs[j];
            }
            rs[i] = sum;
        }
        #pragma unroll
        for (int o = 1; o < 16; o <<= 1) {
            #pragma unroll
            for (int i = 0; i < 4; ++i) rs[i] += __shfl_xor(rs[i], o);
        }
        if (cl == 0) {
            #pragma unroll
            for (int i = 0; i < 4; ++i) {
                const int r = row0 + wm + mi * 16 + q * 4 + i;
                atomicAdd(&score[r], rs[i]);
            }
        }
    }
}

// ---------------------------------------------------------------- k4:
// R6-VERBATIM: fused softmax + awe.  grid (8 e-chunks, 128 b) x 256 thr.
__global__ void k4_awe(const float* __restrict__ enc, const float* __restrict__ score,
                       float* __restrict__ alpha, float* __restrict__ awe) {
    __shared__ float as[NPIX];
    __shared__ float red[4];
    __shared__ f32x4 redv[4][64];
    const int b  = blockIdx.y;
    const int t  = threadIdx.x;
    const int wv = t >> 6, lane = t & 63;
    // --- softmax over P=196 ---
    const float x = (t < NPIX) ? score[b * NPIX + t] : -INFINITY;
    float m = x;
    #pragma unroll
    for (int o = 32; o >= 1; o >>= 1) m = fmaxf(m, __shfl_xor(m, o));
    if (lane == 0) red[wv] = m;
    __syncthreads();
    m = fmaxf(fmaxf(red[0], red[1]), fmaxf(red[2], red[3]));
    const float e = (t < NPIX) ? __expf(x - m) : 0.f;
    float s = e;
    #pragma unroll
    for (int o = 32; o >= 1; o >>= 1) s += __shfl_xor(s, o);
    __syncthreads();
    if (lane == 0) red[wv] = s;
    __syncthreads();
    s = red[0] + red[1] + red[2] + red[3];
    const float a = e / s;
    if (t < NPIX) {
        as[t] = a;
        if (blockIdx.x == 0) alpha[b * NPIX + t] = a;
    }
    __syncthreads();
    // --- awe ---
    const int e0 = blockIdx.x * 256 + lane * 4;
    const float* base = enc + (size_t)b * NPIX * ENC_DIM + e0;
    f32x4 a0 = {}, a1 = {}, a2 = {}, a3 = {};
    int p = wv;
    #pragma unroll 4
    for (int it = 0; it < 12; ++it, p += 16) {
        a0 += as[p]      * *(const f32x4*)(base + (size_t)(p)      * ENC_DIM);
        a1 += as[p + 4]  * *(const f32x4*)(base + (size_t)(p + 4)  * ENC_DIM);
        a2 += as[p + 8]  * *(const f32x4*)(base + (size_t)(p + 8)  * ENC_DIM);
        a3 += as[p + 12] * *(const f32x4*)(base + (size_t)(p + 12) * ENC_DIM);
    }
    a0 += as[p] * *(const f32x4*)(base + (size_t)p * ENC_DIM);   // p = wv + 192 < 196
    redv[wv][lane] = (a0 + a1) + (a2 + a3);
    __syncthreads();
    if (wv == 0) {
        const f32x4 r = (redv[0][lane] + redv[1][lane]) + (redv[2][lane] + redv[3][lane]);
        *(f32x4*)&awe[(size_t)b * ENC_DIM + e0] = r;
    }
}

// ----------------------------------------------------------------
extern "C" void kernel_launch(void* const* d_in, const int* in_sizes, int n_in,
                              void* d_out, int out_size, void* d_ws, size_t ws_size,
                              hipStream_t stream) {
    const float* enc    = (const float*)d_in[0];   // [128,196,2048]
    const float* dh     = (const float*)d_in[1];   // [128,512]
    const float* W_enc  = (const float*)d_in[2];   // [2048,512]
    const float* b_enc  = (const float*)d_in[3];   // [512]
    const float* W_dec  = (const float*)d_in[4];   // [512,512]
    const float* b_dec  = (const float*)d_in[5];   // [512]
    const float* W_full = (const float*)d_in[6];   // [512]
    const float* b_full = (const float*)d_in[7];   // scalar

    float* awe   = (float*)d_out;                  // [128,2048]
    float* alpha = awe + BATCH * ENC_DIM;          // [128,196] final output

    // workspace: Wt bf16 (2 MB) + att2 (256 KB) + score (100 KB)
    unsigned short* Wt    = (unsigned short*)d_ws;
    float*          att2  = (float*)((char*)d_ws + (size_t)ATT_DIM * ENC_DIM * 2);
    float*          score = att2 + (size_t)BATCH * ATT_DIM;

    prep   <<<512,          256, 0, stream>>>(W_enc, dh, W_dec, b_dec, b_enc, b_full,
                                              Wt, att2, score);
    k2_gemm<<<784,          256, 0, stream>>>(enc, Wt, att2, W_full, score);
    k4_awe <<<dim3(8, 128), 256, 0, stream>>>(enc, score, alpha, awe);
}